// Round 1
// 1691.583 us; speedup vs baseline: 1.2401x; 1.2401x over previous
//
#include <hip/hip_runtime.h>

// ---------------------------------------------------------------------------
// LightGCN-style propagation, 4 independent bipartite graphs.
// R5: atomic-free CSR build. The R4 profile showed count_all_kernel at 346us
// (largest single dispatch) with WRITE_SIZE=273MB: 8.8M random device-scope
// atomics write ~32B each through the coherence point at ~25G atomics/s.
// bucket_scatter paid the same 8.8M atomics again. Replacement:
//   K1 count_partial: per-(chunk,bucket) LDS histogram (16K bins, 64KB LDS),
//      flushed with plain coalesced writes -> partial[bucket][chunk][bin].
//   K2 reduce_deg:    deg[d] = sum_c partial  (plain coalesced).
//   K3 exscan (unchanged) -> off[].
//   K4 scatter_nb:    per-(chunk,sub-bucket) LDS cursors seeded with
//      off[d] + sum_{c'<c} partial[d][c'] (disjoint per-chunk sub-ranges =>
//      uniqueness without global atomics); pairs written into ~1MB windows,
//      chunk-blocks of one bucket swizzled onto one XCD for L2 coalescing.
// No hipMemset needed (everything fully overwritten). SpMM path unchanged.
// ---------------------------------------------------------------------------

#define D 128
#define BINS 16384
#define LOG_BINS 14
#define NCHUNK 8

// ---- bf16 helpers (RNE pack, bit-shift unpack) ----
__device__ __forceinline__ unsigned f2bf(float f) {
    unsigned u = __float_as_uint(f);
    u += 0x7FFFu + ((u >> 16) & 1u);
    return u >> 16;
}
__device__ __forceinline__ float bflo(unsigned u) { return __uint_as_float(u << 16); }
__device__ __forceinline__ float bfhi(unsigned u) { return __uint_as_float(u & 0xFFFF0000u); }

// ---- fp32 -> bf16 row conversion (8 elems/thread) ----
__global__ __launch_bounds__(256) void cvt_bf16_kernel(
    const float* __restrict__ x, uint4* __restrict__ y, int n8)
{
    int i = blockIdx.x * 256 + threadIdx.x;
    if (i >= n8) return;
    const float4* xp = (const float4*)x + (size_t)i * 2;
    float4 a = xp[0], b = xp[1];
    uint4 o;
    o.x = f2bf(a.x) | (f2bf(a.y) << 16);
    o.y = f2bf(a.z) | (f2bf(a.w) << 16);
    o.z = f2bf(b.x) | (f2bf(b.y) << 16);
    o.w = f2bf(b.z) | (f2bf(b.w) << 16);
    y[i] = o;
}

// ---- per-(graph,dir) stream descriptor ----
struct Stream {
    const int* dst; const int* src; const float* vals;
    int* deg;            // K2 output (degree, becomes exscan cursor buffer)
    const int* off;      // K4 input (exclusive prefix)
    int2* pairs;         // K4 output
    int nnz, n, bucketBase, sshift;
};
struct Streams8 {
    Stream s[8];
    int* partial;        // [countBucketGlobal][NCHUNK][BINS]
    int sbase[8];        // scatter-bucket base per stream
};

// ---- K1: per-(chunk,bucket) LDS histogram, plain-write flush ----
__global__ __launch_bounds__(512) void count_partial_kernel(Streams8 G)
{
    const Stream S = G.s[blockIdx.z];
    int b = blockIdx.y;
    int nb = (S.n + BINS - 1) >> LOG_BINS;
    if (b >= nb) return;
    int c = blockIdx.x;

    __shared__ int h[BINS];
    for (int i = threadIdx.x; i < BINS; i += 512) h[i] = 0;
    __syncthreads();

    int slice = (((S.nnz + NCHUNK - 1) / NCHUNK) + 3) & ~3;
    int e0 = c * slice;
    int e1 = min(S.nnz, e0 + slice);
    if (e0 < e1) {
        int nq = (e1 - e0) >> 2;
        const int4* dq = (const int4*)(S.dst + e0);
        for (int i = threadIdx.x; i < nq; i += 512) {
            int4 v = dq[i];
            if ((v.x >> LOG_BINS) == b) atomicAdd(&h[v.x & (BINS - 1)], 1);
            if ((v.y >> LOG_BINS) == b) atomicAdd(&h[v.y & (BINS - 1)], 1);
            if ((v.z >> LOG_BINS) == b) atomicAdd(&h[v.z & (BINS - 1)], 1);
            if ((v.w >> LOG_BINS) == b) atomicAdd(&h[v.w & (BINS - 1)], 1);
        }
        for (int e = e0 + (nq << 2) + (int)threadIdx.x; e < e1; e += 512) {
            int d = S.dst[e];
            if ((d >> LOG_BINS) == b) atomicAdd(&h[d & (BINS - 1)], 1);
        }
    }
    __syncthreads();
    int* out = G.partial + ((size_t)(S.bucketBase + b) * NCHUNK + c) * BINS;
    for (int i = threadIdx.x; i < BINS; i += 512) out[i] = h[i];
}

// ---- K2: deg[d] = sum over chunks of partial ----
__global__ __launch_bounds__(256) void reduce_deg_kernel(Streams8 G)
{
    const Stream S = G.s[blockIdx.y];
    int d = blockIdx.x * 256 + threadIdx.x;
    if (d >= S.n) return;
    const int* p = G.partial
        + ((size_t)(S.bucketBase + (d >> LOG_BINS)) * NCHUNK) * BINS
        + (d & (BINS - 1));
    int t = 0;
    #pragma unroll
    for (int c = 0; c < NCHUNK; ++c) t += p[(size_t)c * BINS];
    S.deg[d] = t;
}

// ---- K3: 8 exclusive scans, one workgroup each (unchanged from R4) ----
struct SDesc { int* degcur; int* off; int n; };
struct SDesc8 { SDesc s[8]; };

__global__ __launch_bounds__(1024) void exscan_all_kernel(SDesc8 S)
{
    SDesc sd = S.s[blockIdx.x];
    const int* deg = sd.degcur;
    int* off = sd.off;
    int* cursor = sd.degcur;
    int n = sd.n;

    __shared__ int wsum[16];
    __shared__ int s_carry;
    int tid = threadIdx.x;
    int lane = tid & 63, wid = tid >> 6;
    if (tid == 0) s_carry = 0;
    __syncthreads();
    for (int base = 0; base < n; base += 4096) {
        int i0 = base + tid * 4;
        int v0 = (i0 + 0 < n) ? deg[i0 + 0] : 0;
        int v1 = (i0 + 1 < n) ? deg[i0 + 1] : 0;
        int v2 = (i0 + 2 < n) ? deg[i0 + 2] : 0;
        int v3 = (i0 + 3 < n) ? deg[i0 + 3] : 0;
        int tsum = v0 + v1 + v2 + v3;
        int x = tsum;
        #pragma unroll
        for (int s = 1; s < 64; s <<= 1) {
            int y = __shfl_up(x, s, 64);
            if (lane >= s) x += y;
        }
        if (lane == 63) wsum[wid] = x;
        __syncthreads();
        if (tid == 0) {
            int run = 0;
            #pragma unroll
            for (int w = 0; w < 16; ++w) { int t = wsum[w]; wsum[w] = run; run += t; }
        }
        __syncthreads();
        int carry = s_carry;
        int excl = carry + wsum[wid] + (x - tsum);
        if (i0 + 0 < n) { off[i0 + 0] = excl; cursor[i0 + 0] = excl; }
        excl += v0;
        if (i0 + 1 < n) { off[i0 + 1] = excl; cursor[i0 + 1] = excl; }
        excl += v1;
        if (i0 + 2 < n) { off[i0 + 2] = excl; cursor[i0 + 2] = excl; }
        excl += v2;
        if (i0 + 3 < n) { off[i0 + 3] = excl; cursor[i0 + 3] = excl; }
        excl += v3;
        __syncthreads();
        if (tid == 1023) s_carry = excl;
    }
    __syncthreads();
    if (tid == 0) off[n] = s_carry;
}

// ---- K4: atomic-free scatter with LDS cursors ----
// 1-D grid, 8 chunk-blocks per scatter-bucket. fid%8 selects both the XCD
// (dispatch round-robin) and the bucket's low bits, so all 8 chunks of one
// bucket land on the same XCD -> the bucket's ~1MB pair window coalesces in
// that XCD's L2 before eviction.
__global__ __launch_bounds__(512) void scatter_nb_kernel(Streams8 G)
{
    int fid = blockIdx.x;
    int k = fid & 7, j = fid >> 3;
    int B = (j & ~7) | k;            // global scatter-bucket index
    int c = j & 7;                   // chunk
    int s = 0;
    #pragma unroll
    for (int i = 1; i < 8; ++i) s += (B >= G.sbase[i]);
    const Stream S = G.s[s];
    int b = B - G.sbase[s];
    int sb = 1 << S.sshift;
    int nb = (S.n + sb - 1) >> S.sshift;
    if (b >= nb) return;

    __shared__ int cur[BINS];
    int dbase = b << S.sshift;
    for (int i = threadIdx.x; i < sb; i += 512) {
        int d = dbase + i;
        cur[i] = (d < S.n) ? S.off[d] : 0;
    }
    // add earlier chunks' counts (per-chunk sub-ranges => unique positions)
    {
        const int* pb = G.partial
            + (size_t)(S.bucketBase + (dbase >> LOG_BINS)) * NCHUNK * BINS
            + (dbase & (BINS - 1));
        for (int cc = 0; cc < c; ++cc) {
            const int* p = pb + (size_t)cc * BINS;
            for (int i = threadIdx.x; i < sb; i += 512) {
                if (dbase + i < S.n) cur[i] += p[i];
            }
        }
    }
    __syncthreads();

    int slice = (((S.nnz + NCHUNK - 1) / NCHUNK) + 3) & ~3;
    int e0 = c * slice;
    int e1 = min(S.nnz, e0 + slice);
    if (e0 >= e1) return;
    int nq = (e1 - e0) >> 2;
    const int4* dq = (const int4*)(S.dst + e0);
    int msk = sb - 1;
    for (int i = threadIdx.x; i < nq; i += 512) {
        int4 v = dq[i];
        int e = e0 + (i << 2);
        if ((v.x >> S.sshift) == b) {
            int pos = atomicAdd(&cur[v.x & msk], 1);
            S.pairs[pos] = make_int2(S.src[e + 0], __float_as_int(S.vals[e + 0]));
        }
        if ((v.y >> S.sshift) == b) {
            int pos = atomicAdd(&cur[v.y & msk], 1);
            S.pairs[pos] = make_int2(S.src[e + 1], __float_as_int(S.vals[e + 1]));
        }
        if ((v.z >> S.sshift) == b) {
            int pos = atomicAdd(&cur[v.z & msk], 1);
            S.pairs[pos] = make_int2(S.src[e + 2], __float_as_int(S.vals[e + 2]));
        }
        if ((v.w >> S.sshift) == b) {
            int pos = atomicAdd(&cur[v.w & msk], 1);
            S.pairs[pos] = make_int2(S.src[e + 3], __float_as_int(S.vals[e + 3]));
        }
    }
    for (int e = e0 + (nq << 2) + (int)threadIdx.x; e < e1; e += 512) {
        int d = S.dst[e];
        if ((d >> S.sshift) == b) {
            int pos = atomicAdd(&cur[d & msk], 1);
            S.pairs[pos] = make_int2(S.src[e], __float_as_int(S.vals[e]));
        }
    }
}

// ---- gather SpMM: one wave per row, quarter-wave per edge, bf16 rows ----
// MODE 0: y = acc                          (P-side -> t)
// MODE 1: y = acc; out = aux(emb) + acc    (N-side layer 1)
// MODE 2: y = acc; out += acc              (N-side layer 2)
// MODE 3: out = (out + acc) * 0.25         (N-side layer 3)
template<int MODE>
__global__ __launch_bounds__(256) void spmm_kernel(
    const unsigned short* __restrict__ x,   // bf16 [n_src][128]
    unsigned short* __restrict__ y,         // bf16 [n_dst][128]
    float* __restrict__ out,                // fp32 [n_dst][128]
    const float* __restrict__ aux,          // fp32 emb (MODE 1)
    const int* __restrict__ off, const int2* __restrict__ pairs, int n_dst)
{
    int row = blockIdx.x * 4 + (threadIdx.x >> 6);
    if (row >= n_dst) return;
    int lane = threadIdx.x & 63;
    int q   = lane >> 4;     // quarter 0..3 -> edge j+q
    int l16 = lane & 15;     // elems l16*8 .. l16*8+7

    int s = off[row], e = off[row + 1];
    float acc[8] = {0.f,0.f,0.f,0.f,0.f,0.f,0.f,0.f};

    int j = s;
    for (; j + 7 < e; j += 8) {            // 8 edges/iter, all valid
        int2 p0 = pairs[j + q];
        int2 p1 = pairs[j + 4 + q];
        float v0 = __int_as_float(p0.y);
        float v1 = __int_as_float(p1.y);
        uint4 g0 = ((const uint4*)(x + ((long)p0.x << 7)))[l16];
        uint4 g1 = ((const uint4*)(x + ((long)p1.x << 7)))[l16];
        acc[0] += v0 * bflo(g0.x); acc[1] += v0 * bfhi(g0.x);
        acc[2] += v0 * bflo(g0.y); acc[3] += v0 * bfhi(g0.y);
        acc[4] += v0 * bflo(g0.z); acc[5] += v0 * bfhi(g0.z);
        acc[6] += v0 * bflo(g0.w); acc[7] += v0 * bfhi(g0.w);
        acc[0] += v1 * bflo(g1.x); acc[1] += v1 * bfhi(g1.x);
        acc[2] += v1 * bflo(g1.y); acc[3] += v1 * bfhi(g1.y);
        acc[4] += v1 * bflo(g1.z); acc[5] += v1 * bfhi(g1.z);
        acc[6] += v1 * bflo(g1.w); acc[7] += v1 * bfhi(g1.w);
    }
    for (; j < e; j += 4) {                // predicated tail quad
        if (j + q < e) {
            int2 p = pairs[j + q];
            float v = __int_as_float(p.y);
            uint4 g = ((const uint4*)(x + ((long)p.x << 7)))[l16];
            acc[0] += v * bflo(g.x); acc[1] += v * bfhi(g.x);
            acc[2] += v * bflo(g.y); acc[3] += v * bfhi(g.y);
            acc[4] += v * bflo(g.z); acc[5] += v * bfhi(g.z);
            acc[6] += v * bflo(g.w); acc[7] += v * bfhi(g.w);
        }
    }
    #pragma unroll
    for (int k = 0; k < 8; ++k) {          // combine 4 quarter partials
        acc[k] += __shfl_xor(acc[k], 16);
        acc[k] += __shfl_xor(acc[k], 32);
    }
    if (q != 0) return;
    long rb = (long)row << 7;
    if (MODE != 3) {
        uint4 o;
        o.x = f2bf(acc[0]) | (f2bf(acc[1]) << 16);
        o.y = f2bf(acc[2]) | (f2bf(acc[3]) << 16);
        o.z = f2bf(acc[4]) | (f2bf(acc[5]) << 16);
        o.w = f2bf(acc[6]) | (f2bf(acc[7]) << 16);
        ((uint4*)(y + rb))[l16] = o;
    }
    if (MODE == 1) {
        const float4* ap = (const float4*)(aux + rb) + l16 * 2;
        float4* op = (float4*)(out + rb) + l16 * 2;
        float4 a0 = ap[0], a1 = ap[1];
        a0.x += acc[0]; a0.y += acc[1]; a0.z += acc[2]; a0.w += acc[3];
        a1.x += acc[4]; a1.y += acc[5]; a1.z += acc[6]; a1.w += acc[7];
        op[0] = a0; op[1] = a1;
    } else if (MODE == 2) {
        float4* op = (float4*)(out + rb) + l16 * 2;
        float4 a0 = op[0], a1 = op[1];
        a0.x += acc[0]; a0.y += acc[1]; a0.z += acc[2]; a0.w += acc[3];
        a1.x += acc[4]; a1.y += acc[5]; a1.z += acc[6]; a1.w += acc[7];
        op[0] = a0; op[1] = a1;
    } else if (MODE == 3) {
        float4* op = (float4*)(out + rb) + l16 * 2;
        float4 a0 = op[0], a1 = op[1];
        a0.x = (a0.x + acc[0]) * 0.25f; a0.y = (a0.y + acc[1]) * 0.25f;
        a0.z = (a0.z + acc[2]) * 0.25f; a0.w = (a0.w + acc[3]) * 0.25f;
        a1.x = (a1.x + acc[4]) * 0.25f; a1.y = (a1.y + acc[5]) * 0.25f;
        a1.z = (a1.z + acc[6]) * 0.25f; a1.w = (a1.w + acc[7]) * 0.25f;
        op[0] = a0; op[1] = a1;
    }
}

extern "C" void kernel_launch(void* const* d_in, const int* in_sizes, int n_in,
                              void* d_out, int out_size, void* d_ws, size_t ws_size,
                              hipStream_t stream)
{
    static const int Ns[4] = {100000, 40000, 20000, 10000};
    static const int Ps[4] = { 40000, 100000, 100000, 40000};
    const int maxN = 100000, maxP = 100000;

    int nnz[4];
    for (int g = 0; g < 4; ++g) nnz[g] = in_sizes[4 + g];

    // ---- workspace carve ----
    char* wp = (char*)d_ws;
    auto alloc = [&](size_t bytes) -> void* {
        void* p = (void*)wp; wp += (bytes + 255) & ~(size_t)255; return p;
    };
    unsigned short* cur = (unsigned short*)alloc((size_t)maxN * D * 2);  // bf16, also emb_bf
    unsigned short* t   = (unsigned short*)alloc((size_t)maxP * D * 2);  // bf16
    int* curP[4]; int* curN[4];
    for (int g = 0; g < 4; ++g) {
        curP[g] = (int*)alloc((size_t)Ps[g] * sizeof(int));
        curN[g] = (int*)alloc((size_t)Ns[g] * sizeof(int));
    }
    int* offP[4]; int* offN[4]; int2* pairsP[4]; int2* pairsN[4];
    for (int g = 0; g < 4; ++g) {
        offP[g] = (int*)alloc((size_t)(Ps[g] + 1) * sizeof(int));
        offN[g] = (int*)alloc((size_t)(Ns[g] + 1) * sizeof(int));
    }
    for (int g = 0; g < 4; ++g) {
        pairsP[g] = (int2*)alloc((size_t)nnz[g] * sizeof(int2));
        pairsN[g] = (int2*)alloc((size_t)nnz[g] * sizeof(int2));
    }

    // ---- stream table ----
    // sshift: largest pow2 span with pair window nnz*8*span/n <= ~2MB, cap 14
    auto calc_shift = [](int n, int m) {
        double span_max = 262144.0 * n / m;
        int shift = 0;
        while ((1 << (shift + 1)) <= (int)span_max && shift < 14) ++shift;
        return shift;
    };
    Streams8 SG;
    int bb = 0;       // count-bucket running base (16K bins each)
    int sB = 0;       // scatter-bucket running base
    int maxCB = 0;
    for (int g = 0; g < 4; ++g) {
        const int* rows = (const int*)d_in[8 + 2 * g];
        const int* cols = (const int*)d_in[8 + 2 * g + 1];
        const float* vals = (const float*)d_in[4 + g];
        for (int dir = 0; dir < 2; ++dir) {
            Stream& s = SG.s[2 * g + dir];
            s.dst  = dir ? cols : rows;
            s.src  = dir ? rows : cols;
            s.vals = vals;
            s.nnz  = nnz[g];
            s.n    = dir ? Ns[g] : Ps[g];
            s.deg  = dir ? curN[g] : curP[g];
            s.off  = dir ? offN[g] : offP[g];
            s.pairs = dir ? pairsN[g] : pairsP[g];
            s.bucketBase = bb;
            int cB = (s.n + BINS - 1) >> LOG_BINS;
            if (cB > maxCB) maxCB = cB;
            bb += cB;
            s.sshift = calc_shift(s.n, s.nnz);
            SG.sbase[2 * g + dir] = sB;
            sB += (s.n + (1 << s.sshift) - 1) >> s.sshift;
        }
    }
    // partial[bb][NCHUNK][BINS] aliases cur+t (build fully precedes cvt/spmm)
    SG.partial = (int*)cur;   // bb(=33) * 8 * 64KB = 17.3MB < 25.6MB(cur)

    // ---- CSR build: count -> reduce -> scan -> scatter (no global atomics) ----
    count_partial_kernel<<<dim3(NCHUNK, maxCB, 8), 512, 0, stream>>>(SG);
    reduce_deg_kernel<<<dim3((maxN + 255) / 256, 8), 256, 0, stream>>>(SG);

    SDesc8 S;
    for (int g = 0; g < 4; ++g) {
        S.s[2 * g + 0] = { curP[g], offP[g], Ps[g] };
        S.s[2 * g + 1] = { curN[g], offN[g], Ns[g] };
    }
    exscan_all_kernel<<<8, 1024, 0, stream>>>(S);

    int nbukPad = (sB + 7) & ~7;
    scatter_nb_kernel<<<nbukPad * 8, 512, 0, stream>>>(SG);

    // ---- propagation, per graph (unchanged) ----
    size_t out_off = 0;
    for (int g = 0; g < 4; ++g) {
        const float* emb = (const float*)d_in[g];
        float* outg = (float*)d_out + out_off;
        const int N = Ns[g], P = Ps[g];
        const int gridP = (P + 3) / 4;
        const int gridN = (N + 3) / 4;

        // emb -> bf16 into cur (consumed by layer-1 P-side before overwrite)
        int n8 = N * D / 8;
        cvt_bf16_kernel<<<(n8 + 255) / 256, 256, 0, stream>>>(emb, (uint4*)cur, n8);

        // layer 1
        spmm_kernel<0><<<gridP, 256, 0, stream>>>(cur, t, nullptr, nullptr,
                                                  offP[g], pairsP[g], P);
        spmm_kernel<1><<<gridN, 256, 0, stream>>>(t, cur, outg, emb,
                                                  offN[g], pairsN[g], N);
        // layer 2
        spmm_kernel<0><<<gridP, 256, 0, stream>>>(cur, t, nullptr, nullptr,
                                                  offP[g], pairsP[g], P);
        spmm_kernel<2><<<gridN, 256, 0, stream>>>(t, cur, outg, nullptr,
                                                  offN[g], pairsN[g], N);
        // layer 3
        spmm_kernel<0><<<gridP, 256, 0, stream>>>(cur, t, nullptr, nullptr,
                                                  offP[g], pairsP[g], P);
        spmm_kernel<3><<<gridN, 256, 0, stream>>>(t, nullptr, outg, nullptr,
                                                  offN[g], pairsN[g], N);

        out_off += (size_t)N * D;
    }
}

// Round 2
// 1417.568 us; speedup vs baseline: 1.4798x; 1.1933x over previous
//
#include <hip/hip_runtime.h>

// ---------------------------------------------------------------------------
// LightGCN-style propagation, 4 independent bipartite graphs.
// R6: two-phase radix-partition CSR build (replaces R5's rescan-scatter).
// R5 profile: scatter_nb = 350us/iter, FETCH 312MB (nb-fold dst rescans),
// WRITE 303MB (4.3x amplification: 64 concurrent 2MB windows >> 32MB L2).
// New build, all global traffic coalesced:
//   K1 countB:    1 dst pass, LDS hist of <=512 coarse dest-buckets
//                 -> cnt[bucket][chunk].
//   K2 scanB:     per-stream bucket totals + exscan -> bucket bases and
//                 per-(bucket,chunk) cursor starts (8 tiny blocks).
//   K3 partition: 1 dst+src+val pass, <=512 LDS cursors/block, writes
//                 (src,val) bucket-major into d_out-as-scratch + dst copy
//                 into cur/t-as-scratch. ~nb live write lines/block -> L2
//                 coalesces.
//   K4 permute:   1 block/bucket: coalesced segment read, per-dest LDS
//                 hist+scan over span<=512 (writes CSR off[] directly!),
//                 scatter into 57KB LDS tile, coalesced flush to pairs.
//                 cnt>7168 fallback: direct global scatter (never in practice,
//                 correct anyway; staging!=pairs so no in-place hazard).
// Kills count_partial/reduce_deg/exscan_all (the 16K-bin machinery) too:
// per-dest offsets emerge from K4's local scan. SpMM path unchanged.
// ---------------------------------------------------------------------------

#define D 128
#define NC 64          // partition chunks per stream
#define TILE_CAP 7168  // permute LDS tile capacity (edges)
#define MAX_NB 512     // max dest-buckets per stream

// ---- bf16 helpers (RNE pack, bit-shift unpack) ----
__device__ __forceinline__ unsigned f2bf(float f) {
    unsigned u = __float_as_uint(f);
    u += 0x7FFFu + ((u >> 16) & 1u);
    return u >> 16;
}
__device__ __forceinline__ float bflo(unsigned u) { return __uint_as_float(u << 16); }
__device__ __forceinline__ float bfhi(unsigned u) { return __uint_as_float(u & 0xFFFF0000u); }

// ---- fp32 -> bf16 row conversion (8 elems/thread) ----
__global__ __launch_bounds__(256) void cvt_bf16_kernel(
    const float* __restrict__ x, uint4* __restrict__ y, int n8)
{
    int i = blockIdx.x * 256 + threadIdx.x;
    if (i >= n8) return;
    const float4* xp = (const float4*)x + (size_t)i * 2;
    float4 a = xp[0], b = xp[1];
    uint4 o;
    o.x = f2bf(a.x) | (f2bf(a.y) << 16);
    o.y = f2bf(a.z) | (f2bf(a.w) << 16);
    o.z = f2bf(b.x) | (f2bf(b.y) << 16);
    o.w = f2bf(b.z) | (f2bf(b.w) << 16);
    y[i] = o;
}

// ---- per-(graph,dir) stream descriptor ----
struct BStream {
    const int* dst; const int* src; const float* vals;
    int2* staged;        // K3 output (src,val), bucket-major (d_out scratch)
    int* stagedD;        // K3 dst copy (cur/t scratch)
    int2* pairs;         // final CSR pairs
    int* off;            // final CSR offsets [n+1]
    int nnz, n, wshift, nb, cbase;
};
struct B8 {
    BStream s[8];
    int* cnt;            // [sum(nb+1)][NC]: counts -> cursor starts (K2 rewrite)
    int* gBB;            // [sum(nb+1)]: bucket bases + per-stream sentinel
    int pb[8];           // permute-block base per stream
};

// ---- K1: coarse bucket histogram, one dst pass ----
__global__ __launch_bounds__(256) void countB_kernel(B8 G)
{
    const BStream S = G.s[blockIdx.y];
    int c = blockIdx.x;
    __shared__ int h[MAX_NB];
    for (int i = threadIdx.x; i < S.nb; i += 256) h[i] = 0;
    __syncthreads();
    int len = (((S.nnz + NC - 1) / NC) + 3) & ~3;
    int e0 = c * len, e1 = min(S.nnz, e0 + len);
    if (e0 < e1) {
        int nq = (e1 - e0) >> 2;
        const int4* dq = (const int4*)(S.dst + e0);
        for (int i = threadIdx.x; i < nq; i += 256) {
            int4 v = dq[i];
            atomicAdd(&h[v.x >> S.wshift], 1);
            atomicAdd(&h[v.y >> S.wshift], 1);
            atomicAdd(&h[v.z >> S.wshift], 1);
            atomicAdd(&h[v.w >> S.wshift], 1);
        }
        for (int e = e0 + (nq << 2) + (int)threadIdx.x; e < e1; e += 256)
            atomicAdd(&h[S.dst[e] >> S.wshift], 1);
    }
    __syncthreads();
    int* out = G.cnt + (size_t)S.cbase * NC;
    for (int i = threadIdx.x; i < S.nb; i += 256) out[(size_t)i * NC + c] = h[i];
}

// ---- K2: bucket totals + exscan -> bases and per-chunk cursor starts ----
__global__ __launch_bounds__(512) void scanB_kernel(B8 G)
{
    const BStream S = G.s[blockIdx.x];
    int* cnt = G.cnt + (size_t)S.cbase * NC;
    int* bb  = G.gBB + S.cbase;
    __shared__ int wsum[8];
    int b = threadIdx.x;
    int t = 0;
    if (b < S.nb) {
        int* row = cnt + (size_t)b * NC;
        int run = 0;
        #pragma unroll
        for (int c = 0; c < NC; ++c) { int v = row[c]; row[c] = run; run += v; }
        t = run;
    }
    int lane = b & 63, w = b >> 6;
    int x = t;
    #pragma unroll
    for (int s = 1; s < 64; s <<= 1) {
        int y = __shfl_up(x, s, 64);
        if (lane >= s) x += y;
    }
    if (lane == 63) wsum[w] = x;
    __syncthreads();
    if (b == 0) {
        int run = 0;
        #pragma unroll
        for (int i = 0; i < 8; ++i) { int v = wsum[i]; wsum[i] = run; run += v; }
    }
    __syncthreads();
    int excl = wsum[w] + x - t;
    if (b < S.nb) {
        bb[b] = excl;
        int* row = cnt + (size_t)b * NC;
        #pragma unroll
        for (int c = 0; c < NC; ++c) row[c] += excl;
    }
    if (b == 0) { bb[S.nb] = S.nnz; S.off[S.n] = S.nnz; }
}

// ---- K3: partition edges bucket-major (coalescing via few live cursors) ----
__global__ __launch_bounds__(256) void partition_kernel(B8 G)
{
    const BStream S = G.s[blockIdx.y];
    int c = blockIdx.x;
    __shared__ int cur[MAX_NB];
    const int* cs = G.cnt + (size_t)S.cbase * NC;
    for (int i = threadIdx.x; i < S.nb; i += 256) cur[i] = cs[(size_t)i * NC + c];
    __syncthreads();
    int len = (((S.nnz + NC - 1) / NC) + 3) & ~3;
    int e0 = c * len, e1 = min(S.nnz, e0 + len);
    if (e0 >= e1) return;
    int nq = (e1 - e0) >> 2;
    const int4*   dq = (const int4*)(S.dst + e0);
    const int4*   sq = (const int4*)(S.src + e0);
    const float4* vq = (const float4*)(S.vals + e0);
    for (int i = threadIdx.x; i < nq; i += 256) {
        int4 dv = dq[i]; int4 sv = sq[i]; float4 vv = vq[i];
        int p;
        p = atomicAdd(&cur[dv.x >> S.wshift], 1);
        S.staged[p] = make_int2(sv.x, __float_as_int(vv.x)); S.stagedD[p] = dv.x;
        p = atomicAdd(&cur[dv.y >> S.wshift], 1);
        S.staged[p] = make_int2(sv.y, __float_as_int(vv.y)); S.stagedD[p] = dv.y;
        p = atomicAdd(&cur[dv.z >> S.wshift], 1);
        S.staged[p] = make_int2(sv.z, __float_as_int(vv.z)); S.stagedD[p] = dv.z;
        p = atomicAdd(&cur[dv.w >> S.wshift], 1);
        S.staged[p] = make_int2(sv.w, __float_as_int(vv.w)); S.stagedD[p] = dv.w;
    }
    for (int e = e0 + (nq << 2) + (int)threadIdx.x; e < e1; e += 256) {
        int d = S.dst[e];
        int p = atomicAdd(&cur[d >> S.wshift], 1);
        S.staged[p] = make_int2(S.src[e], __float_as_int(S.vals[e]));
        S.stagedD[p] = d;
    }
}

// ---- K4: per-bucket dest-sort through LDS; writes CSR off[] + pairs ----
__global__ __launch_bounds__(512) void permute_kernel(B8 G)
{
    int gb = blockIdx.x;
    int s = 0;
    #pragma unroll
    for (int i = 1; i < 8; ++i) s += (gb >= G.pb[i]);
    const BStream S = G.s[s];
    int b = gb - G.pb[s];
    const int* bb = G.gBB + S.cbase;
    int B0 = bb[b], B1 = bb[b + 1];
    int cnt = B1 - B0;
    int span = 1 << S.wshift;
    int dbase = b << S.wshift;

    __shared__ int2 tile[TILE_CAP];
    __shared__ int cursor[MAX_NB];
    __shared__ int wsum[8];
    int tid = threadIdx.x;

    for (int i = tid; i < span; i += 512) cursor[i] = 0;
    __syncthreads();
    for (int i = B0 + tid; i < B1; i += 512)
        atomicAdd(&cursor[S.stagedD[i] - dbase], 1);
    __syncthreads();

    // exclusive scan over span (<=512) counts
    int v = (tid < span) ? cursor[tid] : 0;
    int lane = tid & 63, w = tid >> 6;
    int x = v;
    #pragma unroll
    for (int st = 1; st < 64; st <<= 1) {
        int y = __shfl_up(x, st, 64);
        if (lane >= st) x += y;
    }
    if (lane == 63) wsum[w] = x;
    __syncthreads();
    if (tid == 0) {
        int run = 0;
        #pragma unroll
        for (int i = 0; i < 8; ++i) { int t = wsum[i]; wsum[i] = run; run += t; }
    }
    __syncthreads();
    int excl = wsum[w] + x - v;
    __syncthreads();
    if (tid < span) {
        int d = dbase + tid;
        if (d < S.n) S.off[d] = B0 + excl;
        cursor[tid] = excl;
    }
    __syncthreads();

    if (cnt <= TILE_CAP) {
        for (int i = B0 + tid; i < B1; i += 512) {
            int d = S.stagedD[i];
            int p = atomicAdd(&cursor[d - dbase], 1);
            tile[p] = S.staged[i];
        }
        __syncthreads();
        for (int i = tid; i < cnt; i += 512) S.pairs[B0 + i] = tile[i];
    } else {
        // statistically-never fallback; staged != pairs so no in-place hazard
        for (int i = B0 + tid; i < B1; i += 512) {
            int d = S.stagedD[i];
            int p = atomicAdd(&cursor[d - dbase], 1);
            S.pairs[B0 + p] = S.staged[i];
        }
    }
}

// ---- gather SpMM: one wave per row, quarter-wave per edge, bf16 rows ----
// MODE 0: y = acc                          (P-side -> t)
// MODE 1: y = acc; out = aux(emb) + acc    (N-side layer 1)
// MODE 2: y = acc; out += acc              (N-side layer 2)
// MODE 3: out = (out + acc) * 0.25         (N-side layer 3)
template<int MODE>
__global__ __launch_bounds__(256) void spmm_kernel(
    const unsigned short* __restrict__ x,   // bf16 [n_src][128]
    unsigned short* __restrict__ y,         // bf16 [n_dst][128]
    float* __restrict__ out,                // fp32 [n_dst][128]
    const float* __restrict__ aux,          // fp32 emb (MODE 1)
    const int* __restrict__ off, const int2* __restrict__ pairs, int n_dst)
{
    int row = blockIdx.x * 4 + (threadIdx.x >> 6);
    if (row >= n_dst) return;
    int lane = threadIdx.x & 63;
    int q   = lane >> 4;     // quarter 0..3 -> edge j+q
    int l16 = lane & 15;     // elems l16*8 .. l16*8+7

    int s = off[row], e = off[row + 1];
    float acc[8] = {0.f,0.f,0.f,0.f,0.f,0.f,0.f,0.f};

    int j = s;
    for (; j + 7 < e; j += 8) {            // 8 edges/iter, all valid
        int2 p0 = pairs[j + q];
        int2 p1 = pairs[j + 4 + q];
        float v0 = __int_as_float(p0.y);
        float v1 = __int_as_float(p1.y);
        uint4 g0 = ((const uint4*)(x + ((long)p0.x << 7)))[l16];
        uint4 g1 = ((const uint4*)(x + ((long)p1.x << 7)))[l16];
        acc[0] += v0 * bflo(g0.x); acc[1] += v0 * bfhi(g0.x);
        acc[2] += v0 * bflo(g0.y); acc[3] += v0 * bfhi(g0.y);
        acc[4] += v0 * bflo(g0.z); acc[5] += v0 * bfhi(g0.z);
        acc[6] += v0 * bflo(g0.w); acc[7] += v0 * bfhi(g0.w);
        acc[0] += v1 * bflo(g1.x); acc[1] += v1 * bfhi(g1.x);
        acc[2] += v1 * bflo(g1.y); acc[3] += v1 * bfhi(g1.y);
        acc[4] += v1 * bflo(g1.z); acc[5] += v1 * bfhi(g1.z);
        acc[6] += v1 * bflo(g1.w); acc[7] += v1 * bfhi(g1.w);
    }
    for (; j < e; j += 4) {                // predicated tail quad
        if (j + q < e) {
            int2 p = pairs[j + q];
            float v = __int_as_float(p.y);
            uint4 g = ((const uint4*)(x + ((long)p.x << 7)))[l16];
            acc[0] += v * bflo(g.x); acc[1] += v * bfhi(g.x);
            acc[2] += v * bflo(g.y); acc[3] += v * bfhi(g.y);
            acc[4] += v * bflo(g.z); acc[5] += v * bfhi(g.z);
            acc[6] += v * bflo(g.w); acc[7] += v * bfhi(g.w);
        }
    }
    #pragma unroll
    for (int k = 0; k < 8; ++k) {          // combine 4 quarter partials
        acc[k] += __shfl_xor(acc[k], 16);
        acc[k] += __shfl_xor(acc[k], 32);
    }
    if (q != 0) return;
    long rb = (long)row << 7;
    if (MODE != 3) {
        uint4 o;
        o.x = f2bf(acc[0]) | (f2bf(acc[1]) << 16);
        o.y = f2bf(acc[2]) | (f2bf(acc[3]) << 16);
        o.z = f2bf(acc[4]) | (f2bf(acc[5]) << 16);
        o.w = f2bf(acc[6]) | (f2bf(acc[7]) << 16);
        ((uint4*)(y + rb))[l16] = o;
    }
    if (MODE == 1) {
        const float4* ap = (const float4*)(aux + rb) + l16 * 2;
        float4* op = (float4*)(out + rb) + l16 * 2;
        float4 a0 = ap[0], a1 = ap[1];
        a0.x += acc[0]; a0.y += acc[1]; a0.z += acc[2]; a0.w += acc[3];
        a1.x += acc[4]; a1.y += acc[5]; a1.z += acc[6]; a1.w += acc[7];
        op[0] = a0; op[1] = a1;
    } else if (MODE == 2) {
        float4* op = (float4*)(out + rb) + l16 * 2;
        float4 a0 = op[0], a1 = op[1];
        a0.x += acc[0]; a0.y += acc[1]; a0.z += acc[2]; a0.w += acc[3];
        a1.x += acc[4]; a1.y += acc[5]; a1.z += acc[6]; a1.w += acc[7];
        op[0] = a0; op[1] = a1;
    } else if (MODE == 3) {
        float4* op = (float4*)(out + rb) + l16 * 2;
        float4 a0 = op[0], a1 = op[1];
        a0.x = (a0.x + acc[0]) * 0.25f; a0.y = (a0.y + acc[1]) * 0.25f;
        a0.z = (a0.z + acc[2]) * 0.25f; a0.w = (a0.w + acc[3]) * 0.25f;
        a1.x = (a1.x + acc[4]) * 0.25f; a1.y = (a1.y + acc[5]) * 0.25f;
        a1.z = (a1.z + acc[6]) * 0.25f; a1.w = (a1.w + acc[7]) * 0.25f;
        op[0] = a0; op[1] = a1;
    }
}

extern "C" void kernel_launch(void* const* d_in, const int* in_sizes, int n_in,
                              void* d_out, int out_size, void* d_ws, size_t ws_size,
                              hipStream_t stream)
{
    static const int Ns[4] = {100000, 40000, 20000, 10000};
    static const int Ps[4] = { 40000, 100000, 100000, 40000};
    const int maxN = 100000, maxP = 100000;

    int nnz[4];
    for (int g = 0; g < 4; ++g) nnz[g] = in_sizes[4 + g];

    // ---- workspace carve ----
    char* wp = (char*)d_ws;
    auto alloc = [&](size_t bytes) -> void* {
        void* p = (void*)wp; wp += (bytes + 255) & ~(size_t)255; return p;
    };
    unsigned short* cur = (unsigned short*)alloc((size_t)maxN * D * 2);  // bf16
    unsigned short* t   = (unsigned short*)alloc((size_t)maxP * D * 2);  // bf16
    int* offP[4]; int* offN[4]; int2* pairsP[4]; int2* pairsN[4];
    for (int g = 0; g < 4; ++g) {
        offP[g] = (int*)alloc((size_t)(Ps[g] + 1) * sizeof(int));
        offN[g] = (int*)alloc((size_t)(Ns[g] + 1) * sizeof(int));
    }
    for (int g = 0; g < 4; ++g) {
        pairsP[g] = (int2*)alloc((size_t)nnz[g] * sizeof(int2));
        pairsN[g] = (int2*)alloc((size_t)nnz[g] * sizeof(int2));
    }

    // build scratch: staged (src,val) int2 -> d_out (87MB >= 70.4MB, fully
    // overwritten later by spmm MODE1); stagedD int -> cur+t (51.2MB >= 35.2MB)
    int2* stagedBase = (int2*)d_out;
    int*  stagedDBase = (int*)cur;

    // wshift: largest span (pow2, <=512) with expected edges <= 5120/bucket
    auto calc_ws = [](int n, int m) {
        int ws = 0;
        while (ws < 9 && (double)m * (double)(1 << (ws + 1)) <= 5120.0 * n) ++ws;
        while (((n + (1 << ws) - 1) >> ws) > MAX_NB) ++ws;
        return ws;
    };

    B8 G;
    int cbase = 0;   // sentinel-spaced row base into cnt/gBB
    int pbTot = 0;   // permute-block total
    size_t soff = 0; // staged edge offset
    for (int g = 0; g < 4; ++g) {
        const int* rows = (const int*)d_in[8 + 2 * g];
        const int* cols = (const int*)d_in[8 + 2 * g + 1];
        const float* vals = (const float*)d_in[4 + g];
        for (int dir = 0; dir < 2; ++dir) {
            BStream& s = G.s[2 * g + dir];
            s.dst  = dir ? cols : rows;
            s.src  = dir ? rows : cols;
            s.vals = vals;
            s.nnz  = nnz[g];
            s.n    = dir ? Ns[g] : Ps[g];
            s.off  = dir ? offN[g] : offP[g];
            s.pairs = dir ? pairsN[g] : pairsP[g];
            s.staged  = stagedBase + soff;
            s.stagedD = stagedDBase + soff;
            soff += (size_t)nnz[g];
            s.wshift = calc_ws(s.n, s.nnz);
            s.nb = (s.n + (1 << s.wshift) - 1) >> s.wshift;
            s.cbase = cbase;
            G.pb[2 * g + dir] = pbTot;
            cbase += s.nb + 1;
            pbTot += s.nb;
        }
    }
    G.cnt = (int*)alloc((size_t)cbase * NC * sizeof(int));
    G.gBB = (int*)alloc((size_t)cbase * sizeof(int));

    // ---- CSR build: count -> scan -> partition -> permute ----
    countB_kernel<<<dim3(NC, 8), 256, 0, stream>>>(G);
    scanB_kernel<<<8, 512, 0, stream>>>(G);
    partition_kernel<<<dim3(NC, 8), 256, 0, stream>>>(G);
    permute_kernel<<<pbTot, 512, 0, stream>>>(G);

    // ---- propagation, per graph (unchanged) ----
    size_t out_off = 0;
    for (int g = 0; g < 4; ++g) {
        const float* emb = (const float*)d_in[g];
        float* outg = (float*)d_out + out_off;
        const int N = Ns[g], P = Ps[g];
        const int gridP = (P + 3) / 4;
        const int gridN = (N + 3) / 4;

        // emb -> bf16 into cur (consumed by layer-1 P-side before overwrite)
        int n8 = N * D / 8;
        cvt_bf16_kernel<<<(n8 + 255) / 256, 256, 0, stream>>>(emb, (uint4*)cur, n8);

        // layer 1
        spmm_kernel<0><<<gridP, 256, 0, stream>>>(cur, t, nullptr, nullptr,
                                                  offP[g], pairsP[g], P);
        spmm_kernel<1><<<gridN, 256, 0, stream>>>(t, cur, outg, emb,
                                                  offN[g], pairsN[g], N);
        // layer 2
        spmm_kernel<0><<<gridP, 256, 0, stream>>>(cur, t, nullptr, nullptr,
                                                  offP[g], pairsP[g], P);
        spmm_kernel<2><<<gridN, 256, 0, stream>>>(t, cur, outg, nullptr,
                                                  offN[g], pairsN[g], N);
        // layer 3
        spmm_kernel<0><<<gridP, 256, 0, stream>>>(cur, t, nullptr, nullptr,
                                                  offP[g], pairsP[g], P);
        spmm_kernel<3><<<gridN, 256, 0, stream>>>(t, nullptr, outg, nullptr,
                                                  offN[g], pairsN[g], N);

        out_off += (size_t)N * D;
    }
}

// Round 3
// 1364.081 us; speedup vs baseline: 1.5378x; 1.0392x over previous
//
#include <hip/hip_runtime.h>

// ---------------------------------------------------------------------------
// LightGCN-style propagation, 4 independent bipartite graphs.
// R7: packed single-stream staging in the radix partition.
// R6 profile: partition_kernel 137us, WRITE 372MB vs 105.6MB logical (3.5x):
// two write regions (staged int2 + stagedD int) x 1919 buckets x 64 chunks
// of live partial lines ~= 31MB ~= all of aggregate L2 -> lines evict
// between 8B writes. Fix: wshift<=9 (span<=512) and src<2^17, so the edge
// packs into ONE int2: (src | dlocal<<17, val). stagedD deleted. Live-line
// set halves (~2MB/XCD < 4MB L2) -> write amplification ~1x; permute also
// drops the 35MB stagedD read.
// Build: countB -> scanB -> partition (packed) -> permute (unpack, per-dest
// LDS counting sort, writes CSR off[] + final pairs coalesced).
// SpMM path unchanged (cache-BW-bound, bf16 gather, quarter-wave).
// ---------------------------------------------------------------------------

#define D 128
#define NC 64          // partition chunks per stream
#define TILE_CAP 7168  // permute LDS tile capacity (edges)
#define MAX_NB 512     // max dest-buckets per stream

// ---- bf16 helpers (RNE pack, bit-shift unpack) ----
__device__ __forceinline__ unsigned f2bf(float f) {
    unsigned u = __float_as_uint(f);
    u += 0x7FFFu + ((u >> 16) & 1u);
    return u >> 16;
}
__device__ __forceinline__ float bflo(unsigned u) { return __uint_as_float(u << 16); }
__device__ __forceinline__ float bfhi(unsigned u) { return __uint_as_float(u & 0xFFFF0000u); }

// ---- fp32 -> bf16 row conversion (8 elems/thread) ----
__global__ __launch_bounds__(256) void cvt_bf16_kernel(
    const float* __restrict__ x, uint4* __restrict__ y, int n8)
{
    int i = blockIdx.x * 256 + threadIdx.x;
    if (i >= n8) return;
    const float4* xp = (const float4*)x + (size_t)i * 2;
    float4 a = xp[0], b = xp[1];
    uint4 o;
    o.x = f2bf(a.x) | (f2bf(a.y) << 16);
    o.y = f2bf(a.z) | (f2bf(a.w) << 16);
    o.z = f2bf(b.x) | (f2bf(b.y) << 16);
    o.w = f2bf(b.z) | (f2bf(b.w) << 16);
    y[i] = o;
}

// ---- per-(graph,dir) stream descriptor ----
struct BStream {
    const int* dst; const int* src; const float* vals;
    int2* staged;        // K3 output (src|dl<<17, val), bucket-major (d_out)
    int2* pairs;         // final CSR pairs
    int* off;            // final CSR offsets [n+1]
    int nnz, n, wshift, nb, cbase;
};
struct B8 {
    BStream s[8];
    int* cnt;            // [sum(nb+1)][NC]: counts -> cursor starts (K2 rewrite)
    int* gBB;            // [sum(nb+1)]: bucket bases + per-stream sentinel
    int pb[8];           // permute-block base per stream
};

// ---- K1: coarse bucket histogram, one dst pass ----
__global__ __launch_bounds__(256) void countB_kernel(B8 G)
{
    const BStream S = G.s[blockIdx.y];
    int c = blockIdx.x;
    __shared__ int h[MAX_NB];
    for (int i = threadIdx.x; i < S.nb; i += 256) h[i] = 0;
    __syncthreads();
    int len = (((S.nnz + NC - 1) / NC) + 3) & ~3;
    int e0 = c * len, e1 = min(S.nnz, e0 + len);
    if (e0 < e1) {
        int nq = (e1 - e0) >> 2;
        const int4* dq = (const int4*)(S.dst + e0);
        for (int i = threadIdx.x; i < nq; i += 256) {
            int4 v = dq[i];
            atomicAdd(&h[v.x >> S.wshift], 1);
            atomicAdd(&h[v.y >> S.wshift], 1);
            atomicAdd(&h[v.z >> S.wshift], 1);
            atomicAdd(&h[v.w >> S.wshift], 1);
        }
        for (int e = e0 + (nq << 2) + (int)threadIdx.x; e < e1; e += 256)
            atomicAdd(&h[S.dst[e] >> S.wshift], 1);
    }
    __syncthreads();
    int* out = G.cnt + (size_t)S.cbase * NC;
    for (int i = threadIdx.x; i < S.nb; i += 256) out[(size_t)i * NC + c] = h[i];
}

// ---- K2: bucket totals + exscan -> bases and per-chunk cursor starts ----
__global__ __launch_bounds__(512) void scanB_kernel(B8 G)
{
    const BStream S = G.s[blockIdx.x];
    int* cnt = G.cnt + (size_t)S.cbase * NC;
    int* bb  = G.gBB + S.cbase;
    __shared__ int wsum[8];
    int b = threadIdx.x;
    int t = 0;
    if (b < S.nb) {
        int* row = cnt + (size_t)b * NC;
        int run = 0;
        #pragma unroll
        for (int c = 0; c < NC; ++c) { int v = row[c]; row[c] = run; run += v; }
        t = run;
    }
    int lane = b & 63, w = b >> 6;
    int x = t;
    #pragma unroll
    for (int s = 1; s < 64; s <<= 1) {
        int y = __shfl_up(x, s, 64);
        if (lane >= s) x += y;
    }
    if (lane == 63) wsum[w] = x;
    __syncthreads();
    if (b == 0) {
        int run = 0;
        #pragma unroll
        for (int i = 0; i < 8; ++i) { int v = wsum[i]; wsum[i] = run; run += v; }
    }
    __syncthreads();
    int excl = wsum[w] + x - t;
    if (b < S.nb) {
        bb[b] = excl;
        int* row = cnt + (size_t)b * NC;
        #pragma unroll
        for (int c = 0; c < NC; ++c) row[c] += excl;
    }
    if (b == 0) { bb[S.nb] = S.nnz; S.off[S.n] = S.nnz; }
}

// ---- K3: partition edges bucket-major, packed (src|dl<<17, val) ----
__global__ __launch_bounds__(256) void partition_kernel(B8 G)
{
    const BStream S = G.s[blockIdx.y];
    int c = blockIdx.x;
    __shared__ int cur[MAX_NB];
    const int* cs = G.cnt + (size_t)S.cbase * NC;
    for (int i = threadIdx.x; i < S.nb; i += 256) cur[i] = cs[(size_t)i * NC + c];
    __syncthreads();
    int len = (((S.nnz + NC - 1) / NC) + 3) & ~3;
    int e0 = c * len, e1 = min(S.nnz, e0 + len);
    if (e0 >= e1) return;
    int smask = (1 << S.wshift) - 1;
    int nq = (e1 - e0) >> 2;
    const int4*   dq = (const int4*)(S.dst + e0);
    const int4*   sq = (const int4*)(S.src + e0);
    const float4* vq = (const float4*)(S.vals + e0);
    for (int i = threadIdx.x; i < nq; i += 256) {
        int4 dv = dq[i]; int4 sv = sq[i]; float4 vv = vq[i];
        int p;
        p = atomicAdd(&cur[dv.x >> S.wshift], 1);
        S.staged[p] = make_int2(sv.x | ((dv.x & smask) << 17), __float_as_int(vv.x));
        p = atomicAdd(&cur[dv.y >> S.wshift], 1);
        S.staged[p] = make_int2(sv.y | ((dv.y & smask) << 17), __float_as_int(vv.y));
        p = atomicAdd(&cur[dv.z >> S.wshift], 1);
        S.staged[p] = make_int2(sv.z | ((dv.z & smask) << 17), __float_as_int(vv.z));
        p = atomicAdd(&cur[dv.w >> S.wshift], 1);
        S.staged[p] = make_int2(sv.w | ((dv.w & smask) << 17), __float_as_int(vv.w));
    }
    for (int e = e0 + (nq << 2) + (int)threadIdx.x; e < e1; e += 256) {
        int d = S.dst[e];
        int p = atomicAdd(&cur[d >> S.wshift], 1);
        S.staged[p] = make_int2(S.src[e] | ((d & smask) << 17), __float_as_int(S.vals[e]));
    }
}

// ---- K4: per-bucket dest-sort through LDS; writes CSR off[] + pairs ----
__global__ __launch_bounds__(512) void permute_kernel(B8 G)
{
    int gb = blockIdx.x;
    int s = 0;
    #pragma unroll
    for (int i = 1; i < 8; ++i) s += (gb >= G.pb[i]);
    const BStream S = G.s[s];
    int b = gb - G.pb[s];
    const int* bb = G.gBB + S.cbase;
    int B0 = bb[b], B1 = bb[b + 1];
    int cnt = B1 - B0;
    int span = 1 << S.wshift;
    int dbase = b << S.wshift;

    __shared__ int2 tile[TILE_CAP];
    __shared__ int cursor[MAX_NB];
    __shared__ int wsum[8];
    int tid = threadIdx.x;

    for (int i = tid; i < span; i += 512) cursor[i] = 0;
    __syncthreads();
    for (int i = B0 + tid; i < B1; i += 512)
        atomicAdd(&cursor[((unsigned)S.staged[i].x) >> 17], 1);
    __syncthreads();

    // exclusive scan over span (<=512) counts
    int v = (tid < span) ? cursor[tid] : 0;
    int lane = tid & 63, w = tid >> 6;
    int x = v;
    #pragma unroll
    for (int st = 1; st < 64; st <<= 1) {
        int y = __shfl_up(x, st, 64);
        if (lane >= st) x += y;
    }
    if (lane == 63) wsum[w] = x;
    __syncthreads();
    if (tid == 0) {
        int run = 0;
        #pragma unroll
        for (int i = 0; i < 8; ++i) { int t = wsum[i]; wsum[i] = run; run += t; }
    }
    __syncthreads();
    int excl = wsum[w] + x - v;
    __syncthreads();
    if (tid < span) {
        int d = dbase + tid;
        if (d < S.n) S.off[d] = B0 + excl;
        cursor[tid] = excl;
    }
    __syncthreads();

    if (cnt <= TILE_CAP) {
        for (int i = B0 + tid; i < B1; i += 512) {
            int2 pe = S.staged[i];
            int dl = ((unsigned)pe.x) >> 17;
            int p = atomicAdd(&cursor[dl], 1);
            tile[p] = make_int2(pe.x & 0x1FFFF, pe.y);
        }
        __syncthreads();
        for (int i = tid; i < cnt; i += 512) S.pairs[B0 + i] = tile[i];
    } else {
        // statistically-never fallback; staged != pairs so no in-place hazard
        for (int i = B0 + tid; i < B1; i += 512) {
            int2 pe = S.staged[i];
            int dl = ((unsigned)pe.x) >> 17;
            int p = atomicAdd(&cursor[dl], 1);
            S.pairs[B0 + p] = make_int2(pe.x & 0x1FFFF, pe.y);
        }
    }
}

// ---- gather SpMM: one wave per row, quarter-wave per edge, bf16 rows ----
// MODE 0: y = acc                          (P-side -> t)
// MODE 1: y = acc; out = aux(emb) + acc    (N-side layer 1)
// MODE 2: y = acc; out += acc              (N-side layer 2)
// MODE 3: out = (out + acc) * 0.25         (N-side layer 3)
template<int MODE>
__global__ __launch_bounds__(256) void spmm_kernel(
    const unsigned short* __restrict__ x,   // bf16 [n_src][128]
    unsigned short* __restrict__ y,         // bf16 [n_dst][128]
    float* __restrict__ out,                // fp32 [n_dst][128]
    const float* __restrict__ aux,          // fp32 emb (MODE 1)
    const int* __restrict__ off, const int2* __restrict__ pairs, int n_dst)
{
    int row = blockIdx.x * 4 + (threadIdx.x >> 6);
    if (row >= n_dst) return;
    int lane = threadIdx.x & 63;
    int q   = lane >> 4;     // quarter 0..3 -> edge j+q
    int l16 = lane & 15;     // elems l16*8 .. l16*8+7

    int s = off[row], e = off[row + 1];
    float acc[8] = {0.f,0.f,0.f,0.f,0.f,0.f,0.f,0.f};

    int j = s;
    for (; j + 7 < e; j += 8) {            // 8 edges/iter, all valid
        int2 p0 = pairs[j + q];
        int2 p1 = pairs[j + 4 + q];
        float v0 = __int_as_float(p0.y);
        float v1 = __int_as_float(p1.y);
        uint4 g0 = ((const uint4*)(x + ((long)p0.x << 7)))[l16];
        uint4 g1 = ((const uint4*)(x + ((long)p1.x << 7)))[l16];
        acc[0] += v0 * bflo(g0.x); acc[1] += v0 * bfhi(g0.x);
        acc[2] += v0 * bflo(g0.y); acc[3] += v0 * bfhi(g0.y);
        acc[4] += v0 * bflo(g0.z); acc[5] += v0 * bfhi(g0.z);
        acc[6] += v0 * bflo(g0.w); acc[7] += v0 * bfhi(g0.w);
        acc[0] += v1 * bflo(g1.x); acc[1] += v1 * bfhi(g1.x);
        acc[2] += v1 * bflo(g1.y); acc[3] += v1 * bfhi(g1.y);
        acc[4] += v1 * bflo(g1.z); acc[5] += v1 * bfhi(g1.z);
        acc[6] += v1 * bflo(g1.w); acc[7] += v1 * bfhi(g1.w);
    }
    for (; j < e; j += 4) {                // predicated tail quad
        if (j + q < e) {
            int2 p = pairs[j + q];
            float v = __int_as_float(p.y);
            uint4 g = ((const uint4*)(x + ((long)p.x << 7)))[l16];
            acc[0] += v * bflo(g.x); acc[1] += v * bfhi(g.x);
            acc[2] += v * bflo(g.y); acc[3] += v * bfhi(g.y);
            acc[4] += v * bflo(g.z); acc[5] += v * bfhi(g.z);
            acc[6] += v * bflo(g.w); acc[7] += v * bfhi(g.w);
        }
    }
    #pragma unroll
    for (int k = 0; k < 8; ++k) {          // combine 4 quarter partials
        acc[k] += __shfl_xor(acc[k], 16);
        acc[k] += __shfl_xor(acc[k], 32);
    }
    if (q != 0) return;
    long rb = (long)row << 7;
    if (MODE != 3) {
        uint4 o;
        o.x = f2bf(acc[0]) | (f2bf(acc[1]) << 16);
        o.y = f2bf(acc[2]) | (f2bf(acc[3]) << 16);
        o.z = f2bf(acc[4]) | (f2bf(acc[5]) << 16);
        o.w = f2bf(acc[6]) | (f2bf(acc[7]) << 16);
        ((uint4*)(y + rb))[l16] = o;
    }
    if (MODE == 1) {
        const float4* ap = (const float4*)(aux + rb) + l16 * 2;
        float4* op = (float4*)(out + rb) + l16 * 2;
        float4 a0 = ap[0], a1 = ap[1];
        a0.x += acc[0]; a0.y += acc[1]; a0.z += acc[2]; a0.w += acc[3];
        a1.x += acc[4]; a1.y += acc[5]; a1.z += acc[6]; a1.w += acc[7];
        op[0] = a0; op[1] = a1;
    } else if (MODE == 2) {
        float4* op = (float4*)(out + rb) + l16 * 2;
        float4 a0 = op[0], a1 = op[1];
        a0.x += acc[0]; a0.y += acc[1]; a0.z += acc[2]; a0.w += acc[3];
        a1.x += acc[4]; a1.y += acc[5]; a1.z += acc[6]; a1.w += acc[7];
        op[0] = a0; op[1] = a1;
    } else if (MODE == 3) {
        float4* op = (float4*)(out + rb) + l16 * 2;
        float4 a0 = op[0], a1 = op[1];
        a0.x = (a0.x + acc[0]) * 0.25f; a0.y = (a0.y + acc[1]) * 0.25f;
        a0.z = (a0.z + acc[2]) * 0.25f; a0.w = (a0.w + acc[3]) * 0.25f;
        a1.x = (a1.x + acc[4]) * 0.25f; a1.y = (a1.y + acc[5]) * 0.25f;
        a1.z = (a1.z + acc[6]) * 0.25f; a1.w = (a1.w + acc[7]) * 0.25f;
        op[0] = a0; op[1] = a1;
    }
}

extern "C" void kernel_launch(void* const* d_in, const int* in_sizes, int n_in,
                              void* d_out, int out_size, void* d_ws, size_t ws_size,
                              hipStream_t stream)
{
    static const int Ns[4] = {100000, 40000, 20000, 10000};
    static const int Ps[4] = { 40000, 100000, 100000, 40000};
    const int maxN = 100000, maxP = 100000;

    int nnz[4];
    for (int g = 0; g < 4; ++g) nnz[g] = in_sizes[4 + g];

    // ---- workspace carve ----
    char* wp = (char*)d_ws;
    auto alloc = [&](size_t bytes) -> void* {
        void* p = (void*)wp; wp += (bytes + 255) & ~(size_t)255; return p;
    };
    unsigned short* cur = (unsigned short*)alloc((size_t)maxN * D * 2);  // bf16
    unsigned short* t   = (unsigned short*)alloc((size_t)maxP * D * 2);  // bf16
    int* offP[4]; int* offN[4]; int2* pairsP[4]; int2* pairsN[4];
    for (int g = 0; g < 4; ++g) {
        offP[g] = (int*)alloc((size_t)(Ps[g] + 1) * sizeof(int));
        offN[g] = (int*)alloc((size_t)(Ns[g] + 1) * sizeof(int));
    }
    for (int g = 0; g < 4; ++g) {
        pairsP[g] = (int2*)alloc((size_t)nnz[g] * sizeof(int2));
        pairsN[g] = (int2*)alloc((size_t)nnz[g] * sizeof(int2));
    }

    // build scratch: staged packed int2 -> d_out (87MB >= 70.4MB, fully
    // overwritten later by spmm MODE1 after permute consumes it)
    int2* stagedBase = (int2*)d_out;

    // wshift: largest span (pow2, <=512) with expected edges <= 5120/bucket
    auto calc_ws = [](int n, int m) {
        int ws = 0;
        while (ws < 9 && (double)m * (double)(1 << (ws + 1)) <= 5120.0 * n) ++ws;
        while (((n + (1 << ws) - 1) >> ws) > MAX_NB) ++ws;
        return ws;
    };

    B8 G;
    int cbase = 0;   // sentinel-spaced row base into cnt/gBB
    int pbTot = 0;   // permute-block total
    size_t soff = 0; // staged edge offset
    for (int g = 0; g < 4; ++g) {
        const int* rows = (const int*)d_in[8 + 2 * g];
        const int* cols = (const int*)d_in[8 + 2 * g + 1];
        const float* vals = (const float*)d_in[4 + g];
        for (int dir = 0; dir < 2; ++dir) {
            BStream& s = G.s[2 * g + dir];
            s.dst  = dir ? cols : rows;
            s.src  = dir ? rows : cols;
            s.vals = vals;
            s.nnz  = nnz[g];
            s.n    = dir ? Ns[g] : Ps[g];
            s.off  = dir ? offN[g] : offP[g];
            s.pairs = dir ? pairsN[g] : pairsP[g];
            s.staged  = stagedBase + soff;
            soff += (size_t)nnz[g];
            s.wshift = calc_ws(s.n, s.nnz);
            s.nb = (s.n + (1 << s.wshift) - 1) >> s.wshift;
            s.cbase = cbase;
            G.pb[2 * g + dir] = pbTot;
            cbase += s.nb + 1;
            pbTot += s.nb;
        }
    }
    G.cnt = (int*)alloc((size_t)cbase * NC * sizeof(int));
    G.gBB = (int*)alloc((size_t)cbase * sizeof(int));

    // ---- CSR build: count -> scan -> partition -> permute ----
    countB_kernel<<<dim3(NC, 8), 256, 0, stream>>>(G);
    scanB_kernel<<<8, 512, 0, stream>>>(G);
    partition_kernel<<<dim3(NC, 8), 256, 0, stream>>>(G);
    permute_kernel<<<pbTot, 512, 0, stream>>>(G);

    // ---- propagation, per graph (unchanged) ----
    size_t out_off = 0;
    for (int g = 0; g < 4; ++g) {
        const float* emb = (const float*)d_in[g];
        float* outg = (float*)d_out + out_off;
        const int N = Ns[g], P = Ps[g];
        const int gridP = (P + 3) / 4;
        const int gridN = (N + 3) / 4;

        // emb -> bf16 into cur (consumed by layer-1 P-side before overwrite)
        int n8 = N * D / 8;
        cvt_bf16_kernel<<<(n8 + 255) / 256, 256, 0, stream>>>(emb, (uint4*)cur, n8);

        // layer 1
        spmm_kernel<0><<<gridP, 256, 0, stream>>>(cur, t, nullptr, nullptr,
                                                  offP[g], pairsP[g], P);
        spmm_kernel<1><<<gridN, 256, 0, stream>>>(t, cur, outg, emb,
                                                  offN[g], pairsN[g], N);
        // layer 2
        spmm_kernel<0><<<gridP, 256, 0, stream>>>(cur, t, nullptr, nullptr,
                                                  offP[g], pairsP[g], P);
        spmm_kernel<2><<<gridN, 256, 0, stream>>>(t, cur, outg, nullptr,
                                                  offN[g], pairsN[g], N);
        // layer 3
        spmm_kernel<0><<<gridP, 256, 0, stream>>>(cur, t, nullptr, nullptr,
                                                  offP[g], pairsP[g], P);
        spmm_kernel<3><<<gridN, 256, 0, stream>>>(t, nullptr, outg, nullptr,
                                                  offN[g], pairsN[g], N);

        out_off += (size_t)N * D;
    }
}

// Round 5
// 1320.253 us; speedup vs baseline: 1.5888x; 1.0332x over previous
//
#include <hip/hip_runtime.h>

// ---------------------------------------------------------------------------
// LightGCN-style propagation, 4 independent bipartite graphs.
// R8b: compile fix of R8 (__builtin_nontemporal_load needs native clang
// ext_vector_type, not HIP_vector_type structs).
// (a) partition/countB at 512 thr (2x resident waves; R7 showed 2.1 TB/s
// at 15% occupancy = latency-bound, not BW-bound) + nontemporal streaming
// reads (123MB of once-read dst/src/vals was evicting partial write lines
// from per-XCD L2 -> 2.2x write amplification);
// (b) fused multi-graph dispatches: the 4 graphs are independent within a
// layer-side, so 24 spmm + 4 cvt launches collapse to 6 + 1 via 4-entry desc
// tables (needs per-graph cur/t: +64MB ws, runtime-guarded with fallback to
// the shared-buffer sequential path).
// Build: countB -> scanB -> partition (packed (src|dl<<17,val)) -> permute
// (per-bucket LDS counting sort, writes CSR off[] + pairs coalesced).
// SpMM: bf16 gather, quarter-wave per edge, fp32 accum.
// ---------------------------------------------------------------------------

#define D 128
#define NC 64          // partition chunks per stream
#define TILE_CAP 7168  // permute LDS tile capacity (edges)
#define MAX_NB 512     // max dest-buckets per stream

// native clang vectors (accepted by __builtin_nontemporal_load)
typedef int   vint4   __attribute__((ext_vector_type(4)));
typedef float vfloat4 __attribute__((ext_vector_type(4)));

// ---- bf16 helpers (RNE pack, bit-shift unpack) ----
__device__ __forceinline__ unsigned f2bf(float f) {
    unsigned u = __float_as_uint(f);
    u += 0x7FFFu + ((u >> 16) & 1u);
    return u >> 16;
}
__device__ __forceinline__ float bflo(unsigned u) { return __uint_as_float(u << 16); }
__device__ __forceinline__ float bfhi(unsigned u) { return __uint_as_float(u & 0xFFFF0000u); }

// ---- fp32 -> bf16 row conversion, fused over graphs ----
struct CvtG { const float* x; uint4* y; int n8, blkBase; };
struct CvtG4 { CvtG c[4]; };

__global__ __launch_bounds__(256) void cvt_bf16_kernel(CvtG4 Cd)
{
    int blk = blockIdx.x;
    int gi = (blk >= Cd.c[1].blkBase) + (blk >= Cd.c[2].blkBase)
           + (blk >= Cd.c[3].blkBase);
    const CvtG E = Cd.c[gi];
    int i = (blk - E.blkBase) * 256 + threadIdx.x;
    if (i >= E.n8) return;
    const float4* xp = (const float4*)E.x + (size_t)i * 2;
    float4 a = xp[0], b = xp[1];
    uint4 o;
    o.x = f2bf(a.x) | (f2bf(a.y) << 16);
    o.y = f2bf(a.z) | (f2bf(a.w) << 16);
    o.z = f2bf(b.x) | (f2bf(b.y) << 16);
    o.w = f2bf(b.z) | (f2bf(b.w) << 16);
    E.y[i] = o;
}

// ---- per-(graph,dir) stream descriptor ----
struct BStream {
    const int* dst; const int* src; const float* vals;
    int2* staged;        // K3 output (src|dl<<17, val), bucket-major (d_out)
    int2* pairs;         // final CSR pairs
    int* off;            // final CSR offsets [n+1]
    int nnz, n, wshift, nb, cbase;
};
struct B8 {
    BStream s[8];
    int* cnt;            // [sum(nb+1)][NC]: counts -> cursor starts (K2 rewrite)
    int* gBB;            // [sum(nb+1)]: bucket bases + per-stream sentinel
    int pb[8];           // permute-block base per stream
};

// ---- K1: coarse bucket histogram, one dst pass (nt streaming reads) ----
__global__ __launch_bounds__(512) void countB_kernel(B8 G)
{
    const BStream S = G.s[blockIdx.y];
    int c = blockIdx.x;
    __shared__ int h[MAX_NB];
    for (int i = threadIdx.x; i < S.nb; i += 512) h[i] = 0;
    __syncthreads();
    int len = (((S.nnz + NC - 1) / NC) + 3) & ~3;
    int e0 = c * len, e1 = min(S.nnz, e0 + len);
    if (e0 < e1) {
        int nq = (e1 - e0) >> 2;
        const vint4* dq = (const vint4*)(S.dst + e0);
        for (int i = threadIdx.x; i < nq; i += 512) {
            vint4 v = __builtin_nontemporal_load(&dq[i]);
            atomicAdd(&h[v.x >> S.wshift], 1);
            atomicAdd(&h[v.y >> S.wshift], 1);
            atomicAdd(&h[v.z >> S.wshift], 1);
            atomicAdd(&h[v.w >> S.wshift], 1);
        }
        for (int e = e0 + (nq << 2) + (int)threadIdx.x; e < e1; e += 512)
            atomicAdd(&h[S.dst[e] >> S.wshift], 1);
    }
    __syncthreads();
    int* out = G.cnt + (size_t)S.cbase * NC;
    for (int i = threadIdx.x; i < S.nb; i += 512) out[(size_t)i * NC + c] = h[i];
}

// ---- K2: bucket totals + exscan -> bases and per-chunk cursor starts ----
__global__ __launch_bounds__(512) void scanB_kernel(B8 G)
{
    const BStream S = G.s[blockIdx.x];
    int* cnt = G.cnt + (size_t)S.cbase * NC;
    int* bb  = G.gBB + S.cbase;
    __shared__ int wsum[8];
    int b = threadIdx.x;
    int t = 0;
    if (b < S.nb) {
        int* row = cnt + (size_t)b * NC;
        int run = 0;
        #pragma unroll
        for (int c = 0; c < NC; ++c) { int v = row[c]; row[c] = run; run += v; }
        t = run;
    }
    int lane = b & 63, w = b >> 6;
    int x = t;
    #pragma unroll
    for (int s = 1; s < 64; s <<= 1) {
        int y = __shfl_up(x, s, 64);
        if (lane >= s) x += y;
    }
    if (lane == 63) wsum[w] = x;
    __syncthreads();
    if (b == 0) {
        int run = 0;
        #pragma unroll
        for (int i = 0; i < 8; ++i) { int v = wsum[i]; wsum[i] = run; run += v; }
    }
    __syncthreads();
    int excl = wsum[w] + x - t;
    if (b < S.nb) {
        bb[b] = excl;
        int* row = cnt + (size_t)b * NC;
        #pragma unroll
        for (int c = 0; c < NC; ++c) row[c] += excl;
    }
    if (b == 0) { bb[S.nb] = S.nnz; S.off[S.n] = S.nnz; }
}

// ---- K3: partition edges bucket-major, packed (src|dl<<17, val) ----
__global__ __launch_bounds__(512) void partition_kernel(B8 G)
{
    const BStream S = G.s[blockIdx.y];
    int c = blockIdx.x;
    __shared__ int cur[MAX_NB];
    const int* cs = G.cnt + (size_t)S.cbase * NC;
    for (int i = threadIdx.x; i < S.nb; i += 512) cur[i] = cs[(size_t)i * NC + c];
    __syncthreads();
    int len = (((S.nnz + NC - 1) / NC) + 3) & ~3;
    int e0 = c * len, e1 = min(S.nnz, e0 + len);
    if (e0 >= e1) return;
    int smask = (1 << S.wshift) - 1;
    int nq = (e1 - e0) >> 2;
    const vint4*   dq = (const vint4*)(S.dst + e0);
    const vint4*   sq = (const vint4*)(S.src + e0);
    const vfloat4* vq = (const vfloat4*)(S.vals + e0);
    for (int i = threadIdx.x; i < nq; i += 512) {
        vint4 dv = __builtin_nontemporal_load(&dq[i]);
        vint4 sv = __builtin_nontemporal_load(&sq[i]);
        vfloat4 vv = __builtin_nontemporal_load(&vq[i]);
        int p;
        p = atomicAdd(&cur[dv.x >> S.wshift], 1);
        S.staged[p] = make_int2(sv.x | ((dv.x & smask) << 17), __float_as_int(vv.x));
        p = atomicAdd(&cur[dv.y >> S.wshift], 1);
        S.staged[p] = make_int2(sv.y | ((dv.y & smask) << 17), __float_as_int(vv.y));
        p = atomicAdd(&cur[dv.z >> S.wshift], 1);
        S.staged[p] = make_int2(sv.z | ((dv.z & smask) << 17), __float_as_int(vv.z));
        p = atomicAdd(&cur[dv.w >> S.wshift], 1);
        S.staged[p] = make_int2(sv.w | ((dv.w & smask) << 17), __float_as_int(vv.w));
    }
    for (int e = e0 + (nq << 2) + (int)threadIdx.x; e < e1; e += 512) {
        int d = S.dst[e];
        int p = atomicAdd(&cur[d >> S.wshift], 1);
        S.staged[p] = make_int2(S.src[e] | ((d & smask) << 17), __float_as_int(S.vals[e]));
    }
}

// ---- K4: per-bucket dest-sort through LDS; writes CSR off[] + pairs ----
__global__ __launch_bounds__(512) void permute_kernel(B8 G)
{
    int gb = blockIdx.x;
    int s = 0;
    #pragma unroll
    for (int i = 1; i < 8; ++i) s += (gb >= G.pb[i]);
    const BStream S = G.s[s];
    int b = gb - G.pb[s];
    const int* bb = G.gBB + S.cbase;
    int B0 = bb[b], B1 = bb[b + 1];
    int cnt = B1 - B0;
    int span = 1 << S.wshift;
    int dbase = b << S.wshift;

    __shared__ int2 tile[TILE_CAP];
    __shared__ int cursor[MAX_NB];
    __shared__ int wsum[8];
    int tid = threadIdx.x;

    for (int i = tid; i < span; i += 512) cursor[i] = 0;
    __syncthreads();
    for (int i = B0 + tid; i < B1; i += 512)
        atomicAdd(&cursor[((unsigned)S.staged[i].x) >> 17], 1);
    __syncthreads();

    // exclusive scan over span (<=512) counts
    int v = (tid < span) ? cursor[tid] : 0;
    int lane = tid & 63, w = tid >> 6;
    int x = v;
    #pragma unroll
    for (int st = 1; st < 64; st <<= 1) {
        int y = __shfl_up(x, st, 64);
        if (lane >= st) x += y;
    }
    if (lane == 63) wsum[w] = x;
    __syncthreads();
    if (tid == 0) {
        int run = 0;
        #pragma unroll
        for (int i = 0; i < 8; ++i) { int t = wsum[i]; wsum[i] = run; run += t; }
    }
    __syncthreads();
    int excl = wsum[w] + x - v;
    __syncthreads();
    if (tid < span) {
        int d = dbase + tid;
        if (d < S.n) S.off[d] = B0 + excl;
        cursor[tid] = excl;
    }
    __syncthreads();

    if (cnt <= TILE_CAP) {
        for (int i = B0 + tid; i < B1; i += 512) {
            int2 pe = S.staged[i];
            int dl = ((unsigned)pe.x) >> 17;
            int p = atomicAdd(&cursor[dl], 1);
            tile[p] = make_int2(pe.x & 0x1FFFF, pe.y);
        }
        __syncthreads();
        for (int i = tid; i < cnt; i += 512) S.pairs[B0 + i] = tile[i];
    } else {
        // statistically-never fallback; staged != pairs so no in-place hazard
        for (int i = B0 + tid; i < B1; i += 512) {
            int2 pe = S.staged[i];
            int dl = ((unsigned)pe.x) >> 17;
            int p = atomicAdd(&cursor[dl], 1);
            S.pairs[B0 + p] = make_int2(pe.x & 0x1FFFF, pe.y);
        }
    }
}

// ---- gather SpMM, fused over graphs via desc table ----
// MODE 0: y = acc                          (P-side -> t)
// MODE 1: y = acc; out = aux(emb) + acc    (N-side layer 1)
// MODE 2: y = acc; out += acc              (N-side layer 2)
// MODE 3: out = (out + acc) * 0.25         (N-side layer 3)
struct SpmmG {
    const unsigned short* x;   // bf16 [n_src][128]
    unsigned short* y;         // bf16 [n_dst][128]
    float* out;                // fp32 [n_dst][128]
    const float* aux;          // fp32 emb (MODE 1)
    const int* off; const int2* pairs;
    int n_dst, blkBase;
};
struct SpmmG4 { SpmmG g[4]; };

template<int MODE>
__global__ __launch_bounds__(256) void spmm_kernel(SpmmG4 Gd)
{
    int blk = blockIdx.x;
    int gi = (blk >= Gd.g[1].blkBase) + (blk >= Gd.g[2].blkBase)
           + (blk >= Gd.g[3].blkBase);
    const SpmmG E = Gd.g[gi];
    int row = (blk - E.blkBase) * 4 + (threadIdx.x >> 6);
    if (row >= E.n_dst) return;
    int lane = threadIdx.x & 63;
    int q   = lane >> 4;     // quarter 0..3 -> edge j+q
    int l16 = lane & 15;     // elems l16*8 .. l16*8+7

    int s = E.off[row], e = E.off[row + 1];
    float acc[8] = {0.f,0.f,0.f,0.f,0.f,0.f,0.f,0.f};

    int j = s;
    for (; j + 7 < e; j += 8) {            // 8 edges/iter, all valid
        int2 p0 = E.pairs[j + q];
        int2 p1 = E.pairs[j + 4 + q];
        float v0 = __int_as_float(p0.y);
        float v1 = __int_as_float(p1.y);
        uint4 g0 = ((const uint4*)(E.x + ((long)p0.x << 7)))[l16];
        uint4 g1 = ((const uint4*)(E.x + ((long)p1.x << 7)))[l16];
        acc[0] += v0 * bflo(g0.x); acc[1] += v0 * bfhi(g0.x);
        acc[2] += v0 * bflo(g0.y); acc[3] += v0 * bfhi(g0.y);
        acc[4] += v0 * bflo(g0.z); acc[5] += v0 * bfhi(g0.z);
        acc[6] += v0 * bflo(g0.w); acc[7] += v0 * bfhi(g0.w);
        acc[0] += v1 * bflo(g1.x); acc[1] += v1 * bfhi(g1.x);
        acc[2] += v1 * bflo(g1.y); acc[3] += v1 * bfhi(g1.y);
        acc[4] += v1 * bflo(g1.z); acc[5] += v1 * bfhi(g1.z);
        acc[6] += v1 * bflo(g1.w); acc[7] += v1 * bfhi(g1.w);
    }
    for (; j < e; j += 4) {                // predicated tail quad
        if (j + q < e) {
            int2 p = E.pairs[j + q];
            float v = __int_as_float(p.y);
            uint4 g = ((const uint4*)(E.x + ((long)p.x << 7)))[l16];
            acc[0] += v * bflo(g.x); acc[1] += v * bfhi(g.x);
            acc[2] += v * bflo(g.y); acc[3] += v * bfhi(g.y);
            acc[4] += v * bflo(g.z); acc[5] += v * bfhi(g.z);
            acc[6] += v * bflo(g.w); acc[7] += v * bfhi(g.w);
        }
    }
    #pragma unroll
    for (int k = 0; k < 8; ++k) {          // combine 4 quarter partials
        acc[k] += __shfl_xor(acc[k], 16);
        acc[k] += __shfl_xor(acc[k], 32);
    }
    if (q != 0) return;
    long rb = (long)row << 7;
    if (MODE != 3) {
        uint4 o;
        o.x = f2bf(acc[0]) | (f2bf(acc[1]) << 16);
        o.y = f2bf(acc[2]) | (f2bf(acc[3]) << 16);
        o.z = f2bf(acc[4]) | (f2bf(acc[5]) << 16);
        o.w = f2bf(acc[6]) | (f2bf(acc[7]) << 16);
        ((uint4*)(E.y + rb))[l16] = o;
    }
    if (MODE == 1) {
        const float4* ap = (const float4*)(E.aux + rb) + l16 * 2;
        float4* op = (float4*)(E.out + rb) + l16 * 2;
        float4 a0 = ap[0], a1 = ap[1];
        a0.x += acc[0]; a0.y += acc[1]; a0.z += acc[2]; a0.w += acc[3];
        a1.x += acc[4]; a1.y += acc[5]; a1.z += acc[6]; a1.w += acc[7];
        op[0] = a0; op[1] = a1;
    } else if (MODE == 2) {
        float4* op = (float4*)(E.out + rb) + l16 * 2;
        float4 a0 = op[0], a1 = op[1];
        a0.x += acc[0]; a0.y += acc[1]; a0.z += acc[2]; a0.w += acc[3];
        a1.x += acc[4]; a1.y += acc[5]; a1.z += acc[6]; a1.w += acc[7];
        op[0] = a0; op[1] = a1;
    } else if (MODE == 3) {
        float4* op = (float4*)(E.out + rb) + l16 * 2;
        float4 a0 = op[0], a1 = op[1];
        a0.x = (a0.x + acc[0]) * 0.25f; a0.y = (a0.y + acc[1]) * 0.25f;
        a0.z = (a0.z + acc[2]) * 0.25f; a0.w = (a0.w + acc[3]) * 0.25f;
        a1.x = (a1.x + acc[4]) * 0.25f; a1.y = (a1.y + acc[5]) * 0.25f;
        a1.z = (a1.z + acc[6]) * 0.25f; a1.w = (a1.w + acc[7]) * 0.25f;
        op[0] = a0; op[1] = a1;
    }
}

extern "C" void kernel_launch(void* const* d_in, const int* in_sizes, int n_in,
                              void* d_out, int out_size, void* d_ws, size_t ws_size,
                              hipStream_t stream)
{
    static const int Ns[4] = {100000, 40000, 20000, 10000};
    static const int Ps[4] = { 40000, 100000, 100000, 40000};
    const int maxN = 100000, maxP = 100000;

    int nnz[4];
    for (int g = 0; g < 4; ++g) nnz[g] = in_sizes[4 + g];

    // wshift: largest span (pow2, <=512) with expected edges <= 5120/bucket
    auto calc_ws = [](int n, int m) {
        int ws = 0;
        while (ws < 9 && (double)m * (double)(1 << (ws + 1)) <= 5120.0 * n) ++ws;
        while (((n + (1 << ws) - 1) >> ws) > MAX_NB) ++ws;
        return ws;
    };

    // ---- stream geometry (pointer-free) ----
    B8 G;
    int cbase = 0, pbTot = 0;
    for (int g = 0; g < 4; ++g)
        for (int dir = 0; dir < 2; ++dir) {
            BStream& s = G.s[2 * g + dir];
            s.nnz = nnz[g];
            s.n   = dir ? Ns[g] : Ps[g];
            s.wshift = calc_ws(s.n, s.nnz);
            s.nb = (s.n + (1 << s.wshift) - 1) >> s.wshift;
            s.cbase = cbase;
            G.pb[2 * g + dir] = pbTot;
            cbase += s.nb + 1;
            pbTot += s.nb;
        }

    // ---- can we afford per-graph cur/t buffers? ----
    auto padded = [](size_t b) { return (b + 255) & ~(size_t)255; };
    size_t need = 0;
    for (int g = 0; g < 4; ++g) need += padded((size_t)Ns[g] * D * 2)
                                      + padded((size_t)Ps[g] * D * 2);
    for (int g = 0; g < 4; ++g) need += padded((size_t)(Ps[g] + 1) * 4)
                                      + padded((size_t)(Ns[g] + 1) * 4);
    for (int g = 0; g < 4; ++g) need += 2 * padded((size_t)nnz[g] * 8);
    need += padded((size_t)cbase * NC * 4) + padded((size_t)cbase * 4);
    bool perGraph = need <= ws_size;

    // ---- workspace carve ----
    char* wp = (char*)d_ws;
    auto alloc = [&](size_t bytes) -> void* {
        void* p = (void*)wp; wp += (bytes + 255) & ~(size_t)255; return p;
    };
    unsigned short* curG[4]; unsigned short* tG[4];
    if (perGraph) {
        for (int g = 0; g < 4; ++g) {
            curG[g] = (unsigned short*)alloc((size_t)Ns[g] * D * 2);
            tG[g]   = (unsigned short*)alloc((size_t)Ps[g] * D * 2);
        }
    } else {
        unsigned short* cur = (unsigned short*)alloc((size_t)maxN * D * 2);
        unsigned short* t   = (unsigned short*)alloc((size_t)maxP * D * 2);
        for (int g = 0; g < 4; ++g) { curG[g] = cur; tG[g] = t; }
    }
    int* offP[4]; int* offN[4]; int2* pairsP[4]; int2* pairsN[4];
    for (int g = 0; g < 4; ++g) {
        offP[g] = (int*)alloc((size_t)(Ps[g] + 1) * sizeof(int));
        offN[g] = (int*)alloc((size_t)(Ns[g] + 1) * sizeof(int));
    }
    for (int g = 0; g < 4; ++g) {
        pairsP[g] = (int2*)alloc((size_t)nnz[g] * sizeof(int2));
        pairsN[g] = (int2*)alloc((size_t)nnz[g] * sizeof(int2));
    }
    G.cnt = (int*)alloc((size_t)cbase * NC * sizeof(int));
    G.gBB = (int*)alloc((size_t)cbase * sizeof(int));

    // staged packed int2 -> d_out (fully consumed by permute before spmm)
    int2* stagedBase = (int2*)d_out;
    size_t soff = 0;
    for (int g = 0; g < 4; ++g)
        for (int dir = 0; dir < 2; ++dir) {
            BStream& s = G.s[2 * g + dir];
            s.dst  = (const int*)d_in[8 + 2 * g + (dir ? 1 : 0)];
            s.src  = (const int*)d_in[8 + 2 * g + (dir ? 0 : 1)];
            s.vals = (const float*)d_in[4 + g];
            s.off  = dir ? offN[g] : offP[g];
            s.pairs = dir ? pairsN[g] : pairsP[g];
            s.staged = stagedBase + soff;
            soff += (size_t)nnz[g];
        }

    // ---- CSR build: count -> scan -> partition -> permute ----
    countB_kernel<<<dim3(NC, 8), 512, 0, stream>>>(G);
    scanB_kernel<<<8, 512, 0, stream>>>(G);
    partition_kernel<<<dim3(NC, 8), 512, 0, stream>>>(G);
    permute_kernel<<<pbTot, 512, 0, stream>>>(G);

    // ---- propagation ----
    size_t out_off[4]; size_t oo = 0;
    for (int g = 0; g < 4; ++g) { out_off[g] = oo; oo += (size_t)Ns[g] * D; }

    if (perGraph) {
        // one cvt dispatch, then 2 fused spmm dispatches per layer
        CvtG4 C; int cb = 0;
        for (int g = 0; g < 4; ++g) {
            int n8 = Ns[g] * D / 8;
            C.c[g] = { (const float*)d_in[g], (uint4*)curG[g], n8, cb };
            cb += (n8 + 255) / 256;
        }
        cvt_bf16_kernel<<<cb, 256, 0, stream>>>(C);

        SpmmG4 TP, TN;
        int pb = 0, nb = 0;
        for (int g = 0; g < 4; ++g) {
            TP.g[g] = { curG[g], tG[g], nullptr, nullptr,
                        offP[g], pairsP[g], Ps[g], pb };
            pb += (Ps[g] + 3) / 4;
            TN.g[g] = { tG[g], curG[g], (float*)d_out + out_off[g],
                        (const float*)d_in[g], offN[g], pairsN[g], Ns[g], nb };
            nb += (Ns[g] + 3) / 4;
        }
        spmm_kernel<0><<<pb, 256, 0, stream>>>(TP);
        spmm_kernel<1><<<nb, 256, 0, stream>>>(TN);
        spmm_kernel<0><<<pb, 256, 0, stream>>>(TP);
        spmm_kernel<2><<<nb, 256, 0, stream>>>(TN);
        spmm_kernel<0><<<pb, 256, 0, stream>>>(TP);
        spmm_kernel<3><<<nb, 256, 0, stream>>>(TN);
    } else {
        // shared-buffer fallback: per-graph sequential, 1-entry tables
        const int BIG = 0x7FFFFFFF;
        for (int g = 0; g < 4; ++g) {
            const float* emb = (const float*)d_in[g];
            float* outg = (float*)d_out + out_off[g];
            const int N = Ns[g], P = Ps[g];
            int n8 = N * D / 8;
            CvtG4 C;
            C.c[0] = { emb, (uint4*)curG[g], n8, 0 };
            for (int i = 1; i < 4; ++i) C.c[i].blkBase = BIG;
            cvt_bf16_kernel<<<(n8 + 255) / 256, 256, 0, stream>>>(C);

            SpmmG4 TP, TN;
            TP.g[0] = { curG[g], tG[g], nullptr, nullptr,
                        offP[g], pairsP[g], P, 0 };
            TN.g[0] = { tG[g], curG[g], outg, emb, offN[g], pairsN[g], N, 0 };
            for (int i = 1; i < 4; ++i) { TP.g[i].blkBase = BIG; TN.g[i].blkBase = BIG; }
            int gp = (P + 3) / 4, gn = (N + 3) / 4;
            spmm_kernel<0><<<gp, 256, 0, stream>>>(TP);
            spmm_kernel<1><<<gn, 256, 0, stream>>>(TN);
            spmm_kernel<0><<<gp, 256, 0, stream>>>(TP);
            spmm_kernel<2><<<gn, 256, 0, stream>>>(TN);
            spmm_kernel<0><<<gp, 256, 0, stream>>>(TP);
            spmm_kernel<3><<<gn, 256, 0, stream>>>(TN);
        }
    }
}